// Round 5
// baseline (226.014 us; speedup 1.0000x reference)
//
#include <hip/hip_runtime.h>
#include <cstddef>

#define N_ENT   2000
#define GAT_EMB 64
#define HIDDEN  256
#define BATCH   8
#define ALPHA   0.2f

typedef _Float16 half4 __attribute__((ext_vector_type(4)));

// ws byte layout:
//   [0,      8192)   s2f  float[2048]
//   [8192,  12288)   hx   _Float16[2048]
//   [12288, 16384)   hy   _Float16[2048]
//   [16384, 20480)   hz   _Float16[2048]
//   [20480, 28672)   s1f  float[2048]
//   [28672, 124672)  x16  _Float16[6000][8]   (tier 2 only)
#define WS_HX_OFF      8192
#define WS_HY_OFF      12288
#define WS_HZ_OFF      16384
#define WS_S1_OFF      20480
#define WS_TABLE_BYTES 28672
#define WS_X_OFF       28672
#define WS_TIER2_BYTES 124672

__global__ __launch_bounds__(256) void k_init(const float* __restrict__ fc1_b,
                                              float* __restrict__ out) {
    int idx = blockIdx.x * 256 + threadIdx.x;   // [0, 2048)
    out[idx] = fc1_b[idx & (HIDDEN - 1)];
}

__global__ __launch_bounds__(256) void k_prep(const float* __restrict__ emb,
                                              const float* __restrict__ W,
                                              const float* __restrict__ a,
                                              float* __restrict__ ws) {
    __shared__ float sW[GAT_EMB * 3];
    __shared__ float sa[6];
    int t = threadIdx.x;
    if (t < GAT_EMB * 3) sW[t] = W[t];
    if (t < 6)           sa[t] = a[t];
    __syncthreads();
    int i = blockIdx.x * 256 + t;
    if (i >= N_ENT) return;
    const float4* er = (const float4*)(emb + (size_t)i * GAT_EMB);
    float h0 = 0.f, h1 = 0.f, h2 = 0.f;
#pragma unroll
    for (int k4 = 0; k4 < GAT_EMB / 4; ++k4) {
        float4 e4 = er[k4];
        int k = 4 * k4;
        h0 += e4.x * sW[(k + 0) * 3 + 0]; h1 += e4.x * sW[(k + 0) * 3 + 1]; h2 += e4.x * sW[(k + 0) * 3 + 2];
        h0 += e4.y * sW[(k + 1) * 3 + 0]; h1 += e4.y * sW[(k + 1) * 3 + 1]; h2 += e4.y * sW[(k + 1) * 3 + 2];
        h0 += e4.z * sW[(k + 2) * 3 + 0]; h1 += e4.z * sW[(k + 2) * 3 + 1]; h2 += e4.z * sW[(k + 2) * 3 + 2];
        h0 += e4.w * sW[(k + 3) * 3 + 0]; h1 += e4.w * sW[(k + 3) * 3 + 1]; h2 += e4.w * sW[(k + 3) * 3 + 2];
    }
    ws[i] = h0 * sa[3] + h1 * sa[4] + h2 * sa[5];                       // s2 (fp32)
    ((_Float16*)((char*)ws + WS_HX_OFF))[i] = (_Float16)h0;
    ((_Float16*)((char*)ws + WS_HY_OFF))[i] = (_Float16)h1;
    ((_Float16*)((char*)ws + WS_HZ_OFF))[i] = (_Float16)h2;
    ws[WS_S1_OFF / 4 + i] = h0 * sa[0] + h1 * sa[1] + h2 * sa[2];       // s1 (fp32)
}

// 1000 blocks; block g owns entities {2g, 2g+1} x all 8 batches.
// Wave w: entity di=w>>1, batches b0=(w&1)*4 .. +3  -> 4 adj streams/wave.
// j unrolled x2 -> 8 dwordx4 in flight/wave. LDS table fp16-packed: 20.5 KB.
// mode: 0 = recompute table + atomic FC, 1 = ws table + atomic FC, 2 = ws table + x16 store.
__global__ __launch_bounds__(256, 4) void k_main(const float* __restrict__ emb,
                                                 const float* __restrict__ W,
                                                 const float* __restrict__ a,
                                                 const float* __restrict__ fc1_w,
                                                 const int*   __restrict__ adj,
                                                 float* __restrict__ wsf,
                                                 int mode,
                                                 float* __restrict__ out) {
    __shared__ __align__(16) unsigned char smem[20480];
    float*    s2s = (float*)smem;
    _Float16* hxs = (_Float16*)(smem + 8192);
    _Float16* hys = (_Float16*)(smem + 12288);
    _Float16* hzs = (_Float16*)(smem + 16384);
    __shared__ float sW[GAT_EMB * 3];
    __shared__ float sa[6];
    __shared__ float s1sh[2];
    __shared__ float xblk[BATCH][8];   // [b][3*di+d]

    int t  = threadIdx.x;
    int g  = blockIdx.x;
    int i0 = g * 2;

    if (mode != 0) {
        const uint4* src = (const uint4*)wsf;
        uint4* dst = (uint4*)smem;
#pragma unroll
        for (int rep = 0; rep < 5; ++rep) dst[rep * 256 + t] = src[rep * 256 + t];  // 1280 uint4 = 20480 B
    } else {
        if (t < GAT_EMB * 3) sW[t] = W[t];
        if (t < 6)           sa[t] = a[t];
        __syncthreads();
        for (int j = t; j < N_ENT; j += 256) {
            const float4* er = (const float4*)(emb + (size_t)j * GAT_EMB);
            float h0 = 0.f, h1 = 0.f, h2 = 0.f;
#pragma unroll
            for (int k4 = 0; k4 < GAT_EMB / 4; ++k4) {
                float4 e4 = er[k4];
                int k = 4 * k4;
                h0 += e4.x * sW[(k + 0) * 3 + 0]; h1 += e4.x * sW[(k + 0) * 3 + 1]; h2 += e4.x * sW[(k + 0) * 3 + 2];
                h0 += e4.y * sW[(k + 1) * 3 + 0]; h1 += e4.y * sW[(k + 1) * 3 + 1]; h2 += e4.y * sW[(k + 1) * 3 + 2];
                h0 += e4.z * sW[(k + 2) * 3 + 0]; h1 += e4.z * sW[(k + 2) * 3 + 1]; h2 += e4.z * sW[(k + 2) * 3 + 2];
                h0 += e4.w * sW[(k + 3) * 3 + 0]; h1 += e4.w * sW[(k + 3) * 3 + 1]; h2 += e4.w * sW[(k + 3) * 3 + 2];
            }
            s2s[j] = h0 * sa[3] + h1 * sa[4] + h2 * sa[5];
            hxs[j] = (_Float16)h0; hys[j] = (_Float16)h1; hzs[j] = (_Float16)h2;
            if (j == i0 || j == i0 + 1)
                s1sh[j - i0] = h0 * sa[0] + h1 * sa[1] + h2 * sa[2];
        }
    }
    if (t < 2048 - N_ENT) {   // zero the pad so tail lanes stay finite
        int j = N_ENT + t;
        s2s[j] = 0.f; hxs[j] = (_Float16)0; hys[j] = (_Float16)0; hzs[j] = (_Float16)0;
    }
    __syncthreads();

    // ---- Phase 2 ----
    int lane = t & 63;
    int w    = t >> 6;
    int di   = w >> 1;
    int b0   = (w & 1) * 4;
    int i    = i0 + di;
    float s1v = (mode == 0) ? s1sh[di] : wsf[WS_S1_OFF / 4 + i];

    const int* __restrict__ bp[4];
    float ac0[4], ac1[4], ac2[4], ac3[4];
#pragma unroll
    for (int s = 0; s < 4; ++s) {
        bp[s] = adj + ((size_t)(b0 + s) * N_ENT + i) * N_ENT;
        ac0[s] = 0.f; ac1[s] = 0.f; ac2[s] = 0.f; ac3[s] = 0.f;
    }

#pragma unroll 1
    for (int kk = 0; kk < 4; ++kk) {
        int jA = kk * 512 + (lane << 2);   // always < 2000
        int jB = jA + 256;
        bool pB = (jB < N_ENT);
        int jBs = pB ? jB : 0;
        int4 mA[4], mB[4];
#pragma unroll
        for (int s = 0; s < 4; ++s) mA[s] = *(const int4*)(bp[s] + jA);
#pragma unroll
        for (int s = 0; s < 4; ++s) mB[s] = *(const int4*)(bp[s] + jBs);

        float4 s2A = *(const float4*)&s2s[jA];
        float4 s2B = *(const float4*)&s2s[jB];      // jB <= 2044, pad is zeroed
        half4  hxA = *(const half4*)&hxs[jA], hxB = *(const half4*)&hxs[jB];
        half4  hyA = *(const half4*)&hys[jA], hyB = *(const half4*)&hys[jB];
        half4  hzA = *(const half4*)&hzs[jA], hzB = *(const half4*)&hzs[jB];

        float evA[4], evB[4], hAx[4], hAy[4], hAz[4], hBx[4], hBy[4], hBz[4];
#pragma unroll
        for (int q = 0; q < 4; ++q) {
            float e = s1v + ((const float*)&s2A)[q];
            evA[q] = __expf(fmaxf(e, 0.f) + ALPHA * fminf(e, 0.f));
            float f = s1v + ((const float*)&s2B)[q];
            evB[q] = __expf(fmaxf(f, 0.f) + ALPHA * fminf(f, 0.f));
            hAx[q] = (float)hxA[q]; hAy[q] = (float)hyA[q]; hAz[q] = (float)hzA[q];
            hBx[q] = (float)hxB[q]; hBy[q] = (float)hyB[q]; hBz[q] = (float)hzB[q];
        }
        float zB = pB ? 1.0f : 0.0f;
#pragma unroll
        for (int s = 0; s < 4; ++s) {
            const int* ma = (const int*)&mA[s];
            const int* mb = (const int*)&mB[s];
#pragma unroll
            for (int q = 0; q < 4; ++q) {
                float eA = (ma[q] > 0) ? evA[q] : 1.0f;   // expf(9e-15)==1.0f exactly
                ac0[s] += eA; ac1[s] += eA * hAx[q]; ac2[s] += eA * hAy[q]; ac3[s] += eA * hAz[q];
                float eB = ((mb[q] > 0) ? evB[q] : 1.0f) * zB;
                ac0[s] += eB; ac1[s] += eB * hBx[q]; ac2[s] += eB * hBy[q]; ac3[s] += eB * hBz[q];
            }
        }
    }

#pragma unroll
    for (int off = 32; off > 0; off >>= 1)
#pragma unroll
        for (int s = 0; s < 4; ++s) {
            ac0[s] += __shfl_xor(ac0[s], off, 64);
            ac1[s] += __shfl_xor(ac1[s], off, 64);
            ac2[s] += __shfl_xor(ac2[s], off, 64);
            ac3[s] += __shfl_xor(ac3[s], off, 64);
        }

    if (lane == 0) {
#pragma unroll
        for (int s = 0; s < 4; ++s) {
            float inv = 1.f / ac0[s];
            float p0 = ac1[s] * inv, p1 = ac2[s] * inv, p2 = ac3[s] * inv;
            xblk[b0 + s][3 * di + 0] = (p0 > 0.f) ? p0 : expm1f(p0);   // ELU
            xblk[b0 + s][3 * di + 1] = (p1 > 0.f) ? p1 : expm1f(p1);
            xblk[b0 + s][3 * di + 2] = (p2 > 0.f) ? p2 : expm1f(p2);
        }
    }
    __syncthreads();

    // ---- Phase 3 ----
    if (mode == 2) {
        if (t < 48) {   // columns m = 6g..6g+5, all 8 batches -> x16[m][b] fp16
            int b = t & 7, c = t >> 3;
            _Float16* x16 = (_Float16*)((char*)wsf + WS_X_OFF);
            x16[(size_t)(6 * g + c) * 8 + b] = (_Float16)xblk[b][c];
        }
    } else {
        int k = (t + g * 19) & 255;   // stagger the atomic storm across lines
        const float* wr = fc1_w + (size_t)k * (N_ENT * 3) + 6 * g;  // 8-B aligned
        float2 wA = *(const float2*)wr;
        float2 wB = *(const float2*)(wr + 2);
        float2 wC = *(const float2*)(wr + 4);
#pragma unroll
        for (int b = 0; b < BATCH; ++b) {
            float d = xblk[b][0] * wA.x + xblk[b][1] * wA.y
                    + xblk[b][2] * wB.x + xblk[b][3] * wB.y
                    + xblk[b][4] * wC.x + xblk[b][5] * wC.y;
            atomicAdd(&out[b * HIDDEN + k], d);
        }
    }
}

// tier 2 epilogue: out[b,k] = fc1_b[k] + sum_m x16[m][b] * fc1_w[k][m]. Deterministic.
__global__ __launch_bounds__(256) void k_fc(const _Float16* __restrict__ x16,
                                            const float* __restrict__ fc1_w,
                                            const float* __restrict__ fc1_b,
                                            float* __restrict__ out) {
    int t = threadIdx.x, lane = t & 63, w = t >> 6;
    int k = blockIdx.x * 4 + w;   // [0,256)
    const float* __restrict__ wr = fc1_w + (size_t)k * (N_ENT * 3);
    float acc[BATCH];
#pragma unroll
    for (int b = 0; b < BATCH; ++b) acc[b] = 0.f;
#pragma unroll 1
    for (int it = 0; it < 24; ++it) {
        int m0 = it * 256 + (lane << 2);
        if (m0 < N_ENT * 3) {
            float4 wv4 = *(const float4*)(wr + m0);
#pragma unroll
            for (int q = 0; q < 4; ++q) {
                half4 xa = *(const half4*)(x16 + (size_t)(m0 + q) * 8);
                half4 xb = *(const half4*)(x16 + (size_t)(m0 + q) * 8 + 4);
                float wv = ((const float*)&wv4)[q];
                acc[0] += wv * (float)xa[0]; acc[1] += wv * (float)xa[1];
                acc[2] += wv * (float)xa[2]; acc[3] += wv * (float)xa[3];
                acc[4] += wv * (float)xb[0]; acc[5] += wv * (float)xb[1];
                acc[6] += wv * (float)xb[2]; acc[7] += wv * (float)xb[3];
            }
        }
    }
#pragma unroll
    for (int off = 32; off > 0; off >>= 1)
#pragma unroll
        for (int b = 0; b < BATCH; ++b) acc[b] += __shfl_xor(acc[b], off, 64);
    if (lane == 0) {
        float bias = fc1_b[k];
#pragma unroll
        for (int b = 0; b < BATCH; ++b) out[b * HIDDEN + k] = acc[b] + bias;
    }
}

extern "C" void kernel_launch(void* const* d_in, const int* in_sizes, int n_in,
                              void* d_out, int out_size, void* d_ws, size_t ws_size,
                              hipStream_t stream) {
    const float* emb   = (const float*)d_in[0];
    const float* W     = (const float*)d_in[1];
    const float* a     = (const float*)d_in[2];
    const float* fc1_w = (const float*)d_in[3];
    const float* fc1_b = (const float*)d_in[4];
    const int*   adj   = (const int*)d_in[5];
    float* out = (float*)d_out;
    float* ws  = (float*)d_ws;
    (void)in_sizes; (void)n_in; (void)out_size;

    // Tier by ws_size (constant across calls -> graph-safe). Round-1 lesson: never exceed ws_size.
    int tier = (ws_size >= (size_t)WS_TIER2_BYTES) ? 2
             : (ws_size >= (size_t)WS_TABLE_BYTES) ? 1 : 0;

    if (tier < 2)  k_init<<<8, 256, 0, stream>>>(fc1_b, out);
    if (tier >= 1) k_prep<<<8, 256, 0, stream>>>(emb, W, a, ws);
    k_main<<<N_ENT / 2, 256, 0, stream>>>(emb, W, a, fc1_w, adj, ws, tier, out);
    if (tier == 2)
        k_fc<<<64, 256, 0, stream>>>((const _Float16*)((char*)d_ws + WS_X_OFF),
                                     fc1_w, fc1_b, out);
}

// Round 6
// 215.196 us; speedup vs baseline: 1.0503x; 1.0503x over previous
//
#include <hip/hip_runtime.h>
#include <cstddef>

#define N_ENT   2000
#define GAT_EMB 64
#define HIDDEN  256
#define BATCH   8
#define ALPHA   0.2f

typedef _Float16 half4 __attribute__((ext_vector_type(4)));

// ws byte layout:
//   [0,      8192)   s2f  float[2048]
//   [8192,  12288)   hx   _Float16[2048]
//   [12288, 16384)   hy   _Float16[2048]
//   [16384, 20480)   hz   _Float16[2048]
//   [20480, 28672)   s1f  float[2048]
//   [28672, 124672)  x16  _Float16[6000][8]   (tier 2 only)
#define WS_HX_OFF      8192
#define WS_HY_OFF      12288
#define WS_HZ_OFF      16384
#define WS_S1_OFF      20480
#define WS_TABLE_BYTES 28672
#define WS_X_OFF       28672
#define WS_TIER2_BYTES 124672

__global__ __launch_bounds__(256) void k_init(const float* __restrict__ fc1_b,
                                              float* __restrict__ out) {
    int idx = blockIdx.x * 256 + threadIdx.x;   // [0, 2048)
    out[idx] = fc1_b[idx & (HIDDEN - 1)];
}

__global__ __launch_bounds__(256) void k_prep(const float* __restrict__ emb,
                                              const float* __restrict__ W,
                                              const float* __restrict__ a,
                                              float* __restrict__ ws) {
    __shared__ float sW[GAT_EMB * 3];
    __shared__ float sa[6];
    int t = threadIdx.x;
    if (t < GAT_EMB * 3) sW[t] = W[t];
    if (t < 6)           sa[t] = a[t];
    __syncthreads();
    int i = blockIdx.x * 256 + t;
    if (i >= N_ENT) return;
    const float4* er = (const float4*)(emb + (size_t)i * GAT_EMB);
    float h0 = 0.f, h1 = 0.f, h2 = 0.f;
#pragma unroll
    for (int k4 = 0; k4 < GAT_EMB / 4; ++k4) {
        float4 e4 = er[k4];
        int k = 4 * k4;
        h0 += e4.x * sW[(k + 0) * 3 + 0]; h1 += e4.x * sW[(k + 0) * 3 + 1]; h2 += e4.x * sW[(k + 0) * 3 + 2];
        h0 += e4.y * sW[(k + 1) * 3 + 0]; h1 += e4.y * sW[(k + 1) * 3 + 1]; h2 += e4.y * sW[(k + 1) * 3 + 2];
        h0 += e4.z * sW[(k + 2) * 3 + 0]; h1 += e4.z * sW[(k + 2) * 3 + 1]; h2 += e4.z * sW[(k + 2) * 3 + 2];
        h0 += e4.w * sW[(k + 3) * 3 + 0]; h1 += e4.w * sW[(k + 3) * 3 + 1]; h2 += e4.w * sW[(k + 3) * 3 + 2];
    }
    ws[i] = h0 * sa[3] + h1 * sa[4] + h2 * sa[5];                       // s2 (fp32)
    ((_Float16*)((char*)ws + WS_HX_OFF))[i] = (_Float16)h0;
    ((_Float16*)((char*)ws + WS_HY_OFF))[i] = (_Float16)h1;
    ((_Float16*)((char*)ws + WS_HZ_OFF))[i] = (_Float16)h2;
    ws[WS_S1_OFF / 4 + i] = h0 * sa[0] + h1 * sa[1] + h2 * sa[2];       // s1 (fp32)
}

// 2000 blocks; block g = entity g, all 8 batches. Wave w: batches {2w, 2w+1}.
// j-loop: 8 chunks of 256 (lane*4 within chunk), FULLY UNROLLED so the compiler
// hoists up to 16 dwordx4 per wave; chunk order rotated per (g,w) to decorrelate
// the 8KB/16MB row strides across HBM channels / L3 slices.
// mode: 0 = recompute table + atomic FC, 1 = ws table + atomic FC, 2 = ws table + x16 store.
__global__ __launch_bounds__(256, 5) void k_main(const float* __restrict__ emb,
                                                 const float* __restrict__ W,
                                                 const float* __restrict__ a,
                                                 const float* __restrict__ fc1_w,
                                                 const int*   __restrict__ adj,
                                                 float* __restrict__ wsf,
                                                 int mode,
                                                 float* __restrict__ out) {
    __shared__ __align__(16) unsigned char smem[20480];
    float*    s2s = (float*)smem;
    _Float16* hxs = (_Float16*)(smem + 8192);
    _Float16* hys = (_Float16*)(smem + 12288);
    _Float16* hzs = (_Float16*)(smem + 16384);
    __shared__ float sW[GAT_EMB * 3];
    __shared__ float sa[6];
    __shared__ float s1sh[1];
    __shared__ float xblk[BATCH][4];   // [b][d], d<3

    int t = threadIdx.x;
    int g = blockIdx.x;                 // entity

    if (mode != 0) {
        const uint4* src = (const uint4*)wsf;
        uint4* dst = (uint4*)smem;
#pragma unroll
        for (int rep = 0; rep < 5; ++rep) dst[rep * 256 + t] = src[rep * 256 + t];  // 20480 B
    } else {
        if (t < GAT_EMB * 3) sW[t] = W[t];
        if (t < 6)           sa[t] = a[t];
        __syncthreads();
        for (int j = t; j < N_ENT; j += 256) {
            const float4* er = (const float4*)(emb + (size_t)j * GAT_EMB);
            float h0 = 0.f, h1 = 0.f, h2 = 0.f;
#pragma unroll
            for (int k4 = 0; k4 < GAT_EMB / 4; ++k4) {
                float4 e4 = er[k4];
                int k = 4 * k4;
                h0 += e4.x * sW[(k + 0) * 3 + 0]; h1 += e4.x * sW[(k + 0) * 3 + 1]; h2 += e4.x * sW[(k + 0) * 3 + 2];
                h0 += e4.y * sW[(k + 1) * 3 + 0]; h1 += e4.y * sW[(k + 1) * 3 + 1]; h2 += e4.y * sW[(k + 1) * 3 + 2];
                h0 += e4.z * sW[(k + 2) * 3 + 0]; h1 += e4.z * sW[(k + 2) * 3 + 1]; h2 += e4.z * sW[(k + 2) * 3 + 2];
                h0 += e4.w * sW[(k + 3) * 3 + 0]; h1 += e4.w * sW[(k + 3) * 3 + 1]; h2 += e4.w * sW[(k + 3) * 3 + 2];
            }
            s2s[j] = h0 * sa[3] + h1 * sa[4] + h2 * sa[5];
            hxs[j] = (_Float16)h0; hys[j] = (_Float16)h1; hzs[j] = (_Float16)h2;
            if (j == g) s1sh[0] = h0 * sa[0] + h1 * sa[1] + h2 * sa[2];
        }
    }
    if (t < 2048 - N_ENT) {   // zero the pad so tail lanes stay finite
        int j = N_ENT + t;
        s2s[j] = 0.f; hxs[j] = (_Float16)0; hys[j] = (_Float16)0; hzs[j] = (_Float16)0;
    }
    __syncthreads();

    // ---- Phase 2: one entity, wave w handles 2 batch streams ----
    int lane = t & 63;
    int w    = t >> 6;
    float s1v = (mode == 0) ? s1sh[0] : wsf[WS_S1_OFF / 4 + g];
    const int* __restrict__ baseA = adj + ((size_t)(2 * w + 0) * N_ENT + g) * N_ENT;
    const int* __restrict__ baseB = adj + ((size_t)(2 * w + 1) * N_ENT + g) * N_ENT;
    int phase = (g + 3 * w) & 7;
    int l4 = lane << 2;

    float aA0 = 0.f, aA1 = 0.f, aA2 = 0.f, aA3 = 0.f;
    float aB0 = 0.f, aB1 = 0.f, aB2 = 0.f, aB3 = 0.f;

#pragma unroll
    for (int s = 0; s < 8; ++s) {
        int c  = (s + phase) & 7;
        int j0 = c * 256 + l4;            // <= 2044
        bool valid = (j0 < N_ENT);
        int jc = valid ? j0 : 0;
        int4 mA = *(const int4*)(baseA + jc);
        int4 mB = *(const int4*)(baseB + jc);
        float4 s2v = *(const float4*)&s2s[j0];   // pad zeroed
        half4  hxv = *(const half4*)&hxs[j0];
        half4  hyv = *(const half4*)&hys[j0];
        half4  hzv = *(const half4*)&hzs[j0];
        float vw = valid ? 1.0f : 0.0f;
        float ev[4], hx[4], hy[4], hz[4];
#pragma unroll
        for (int q = 0; q < 4; ++q) {
            float e = s1v + ((const float*)&s2v)[q];
            ev[q] = __expf(fmaxf(e, 0.f) + ALPHA * fminf(e, 0.f)) ;
            hx[q] = (float)hxv[q]; hy[q] = (float)hyv[q]; hz[q] = (float)hzv[q];
        }
        const int* ma = (const int*)&mA;
        const int* mb = (const int*)&mB;
#pragma unroll
        for (int q = 0; q < 4; ++q) {
            float eA = ((ma[q] > 0) ? ev[q] : 1.0f) * vw;   // expf(9e-15)==1.0f exactly
            aA0 += eA; aA1 += eA * hx[q]; aA2 += eA * hy[q]; aA3 += eA * hz[q];
            float eB = ((mb[q] > 0) ? ev[q] : 1.0f) * vw;
            aB0 += eB; aB1 += eB * hx[q]; aB2 += eB * hy[q]; aB3 += eB * hz[q];
        }
    }

#pragma unroll
    for (int off = 32; off > 0; off >>= 1) {
        aA0 += __shfl_xor(aA0, off, 64); aA1 += __shfl_xor(aA1, off, 64);
        aA2 += __shfl_xor(aA2, off, 64); aA3 += __shfl_xor(aA3, off, 64);
        aB0 += __shfl_xor(aB0, off, 64); aB1 += __shfl_xor(aB1, off, 64);
        aB2 += __shfl_xor(aB2, off, 64); aB3 += __shfl_xor(aB3, off, 64);
    }
    if (lane == 0) {
        float inv = 1.f / aA0;
        float p0 = aA1 * inv, p1 = aA2 * inv, p2 = aA3 * inv;
        xblk[2 * w + 0][0] = (p0 > 0.f) ? p0 : expm1f(p0);
        xblk[2 * w + 0][1] = (p1 > 0.f) ? p1 : expm1f(p1);
        xblk[2 * w + 0][2] = (p2 > 0.f) ? p2 : expm1f(p2);
        inv = 1.f / aB0;
        p0 = aB1 * inv; p1 = aB2 * inv; p2 = aB3 * inv;
        xblk[2 * w + 1][0] = (p0 > 0.f) ? p0 : expm1f(p0);
        xblk[2 * w + 1][1] = (p1 > 0.f) ? p1 : expm1f(p1);
        xblk[2 * w + 1][2] = (p2 > 0.f) ? p2 : expm1f(p2);
    }
    __syncthreads();

    // ---- Phase 3 ----
    if (mode == 2) {
        if (t < 24) {   // columns m = 3g..3g+2, all 8 batches -> x16[m][b] fp16
            int b = t & 7, c = t >> 3;
            _Float16* x16 = (_Float16*)((char*)wsf + WS_X_OFF);
            x16[(size_t)(3 * g + c) * 8 + b] = (_Float16)xblk[b][c];
        }
    } else {
        int k = (t + g * 19) & 255;   // stagger the atomic storm
        const float* wr = fc1_w + (size_t)k * (N_ENT * 3) + 3 * g;
        float w0 = wr[0], w1 = wr[1], w2 = wr[2];
#pragma unroll
        for (int b = 0; b < BATCH; ++b) {
            float d = xblk[b][0] * w0 + xblk[b][1] * w1 + xblk[b][2] * w2;
            atomicAdd(&out[b * HIDDEN + k], d);
        }
    }
}

// tier-2 epilogue: out[b,k] = fc1_b[k] + sum_m x16[m][b] * fc1_w[k][m].
// 256 blocks (one per k), 256 threads; thread t covers m = 4t + 1024*it.
__global__ __launch_bounds__(256) void k_fc(const _Float16* __restrict__ x16,
                                            const float* __restrict__ fc1_w,
                                            const float* __restrict__ fc1_b,
                                            float* __restrict__ out) {
    __shared__ float red[4][8];
    int t = threadIdx.x, lane = t & 63, w = t >> 6;
    int k = blockIdx.x;
    const float* __restrict__ wr = fc1_w + (size_t)k * (N_ENT * 3);
    float acc[BATCH];
#pragma unroll
    for (int b = 0; b < BATCH; ++b) acc[b] = 0.f;
#pragma unroll
    for (int it = 0; it < 6; ++it) {
        int m0 = 4 * t + 1024 * it;
        if (m0 + 3 < N_ENT * 3) {
            float4 wv4 = *(const float4*)(wr + m0);
#pragma unroll
            for (int q = 0; q < 4; ++q) {
                half4 xa = *(const half4*)(x16 + (size_t)(m0 + q) * 8);
                half4 xb = *(const half4*)(x16 + (size_t)(m0 + q) * 8 + 4);
                float wv = ((const float*)&wv4)[q];
                acc[0] += wv * (float)xa[0]; acc[1] += wv * (float)xa[1];
                acc[2] += wv * (float)xa[2]; acc[3] += wv * (float)xa[3];
                acc[4] += wv * (float)xb[0]; acc[5] += wv * (float)xb[1];
                acc[6] += wv * (float)xb[2]; acc[7] += wv * (float)xb[3];
            }
        }
    }
#pragma unroll
    for (int off = 32; off > 0; off >>= 1)
#pragma unroll
        for (int b = 0; b < BATCH; ++b) acc[b] += __shfl_xor(acc[b], off, 64);
    if (lane == 0)
#pragma unroll
        for (int b = 0; b < BATCH; ++b) red[w][b] = acc[b];
    __syncthreads();
    if (t < 8) {
        float s = red[0][t] + red[1][t] + red[2][t] + red[3][t] + fc1_b[k];
        out[t * HIDDEN + k] = s;
    }
}

extern "C" void kernel_launch(void* const* d_in, const int* in_sizes, int n_in,
                              void* d_out, int out_size, void* d_ws, size_t ws_size,
                              hipStream_t stream) {
    const float* emb   = (const float*)d_in[0];
    const float* W     = (const float*)d_in[1];
    const float* a     = (const float*)d_in[2];
    const float* fc1_w = (const float*)d_in[3];
    const float* fc1_b = (const float*)d_in[4];
    const int*   adj   = (const int*)d_in[5];
    float* out = (float*)d_out;
    float* ws  = (float*)d_ws;
    (void)in_sizes; (void)n_in; (void)out_size;

    int tier = (ws_size >= (size_t)WS_TIER2_BYTES) ? 2
             : (ws_size >= (size_t)WS_TABLE_BYTES) ? 1 : 0;

    if (tier < 2)  k_init<<<8, 256, 0, stream>>>(fc1_b, out);
    if (tier >= 1) k_prep<<<8, 256, 0, stream>>>(emb, W, a, ws);
    k_main<<<N_ENT, 256, 0, stream>>>(emb, W, a, fc1_w, adj, ws, tier, out);
    if (tier == 2)
        k_fc<<<HIDDEN, 256, 0, stream>>>((const _Float16*)((char*)d_ws + WS_X_OFF),
                                         fc1_w, fc1_b, out);
}

// Round 7
// 214.845 us; speedup vs baseline: 1.0520x; 1.0016x over previous
//
#include <hip/hip_runtime.h>
#include <cstddef>

#define N_ENT   2000
#define GAT_EMB 64
#define HIDDEN  256
#define BATCH   8
#define ALPHA   0.2f

typedef _Float16 half4 __attribute__((ext_vector_type(4)));

// ws byte layout:
//   [0,      8192)   s2f  float[2048]
//   [8192,  12288)   hx   _Float16[2048]
//   [12288, 16384)   hy   _Float16[2048]
//   [16384, 20480)   hz   _Float16[2048]
//   [20480, 28672)   s1f  float[2048]
//   [28672, 124672)  x16  _Float16[6000][8]
#define WS_HX_OFF      8192
#define WS_HY_OFF      12288
#define WS_HZ_OFF      16384
#define WS_S1_OFF      20480
#define WS_TABLE_BYTES 28672
#define WS_X_OFF       28672
#define WS_TIER2_BYTES 124672

__global__ __launch_bounds__(256) void k_init(const float* __restrict__ fc1_b,
                                              float* __restrict__ out) {
    int idx = blockIdx.x * 256 + threadIdx.x;
    out[idx] = fc1_b[idx & (HIDDEN - 1)];
}

__global__ __launch_bounds__(256) void k_prep(const float* __restrict__ emb,
                                              const float* __restrict__ W,
                                              const float* __restrict__ a,
                                              float* __restrict__ ws) {
    __shared__ float sW[GAT_EMB * 3];
    __shared__ float sa[6];
    int t = threadIdx.x;
    if (t < GAT_EMB * 3) sW[t] = W[t];
    if (t < 6)           sa[t] = a[t];
    __syncthreads();
    int i = blockIdx.x * 256 + t;
    if (i >= N_ENT) return;
    const float4* er = (const float4*)(emb + (size_t)i * GAT_EMB);
    float h0 = 0.f, h1 = 0.f, h2 = 0.f;
#pragma unroll
    for (int k4 = 0; k4 < GAT_EMB / 4; ++k4) {
        float4 e4 = er[k4];
        int k = 4 * k4;
        h0 += e4.x * sW[(k + 0) * 3 + 0]; h1 += e4.x * sW[(k + 0) * 3 + 1]; h2 += e4.x * sW[(k + 0) * 3 + 2];
        h0 += e4.y * sW[(k + 1) * 3 + 0]; h1 += e4.y * sW[(k + 1) * 3 + 1]; h2 += e4.y * sW[(k + 1) * 3 + 2];
        h0 += e4.z * sW[(k + 2) * 3 + 0]; h1 += e4.z * sW[(k + 2) * 3 + 1]; h2 += e4.z * sW[(k + 2) * 3 + 2];
        h0 += e4.w * sW[(k + 3) * 3 + 0]; h1 += e4.w * sW[(k + 3) * 3 + 1]; h2 += e4.w * sW[(k + 3) * 3 + 2];
    }
    ws[i] = h0 * sa[3] + h1 * sa[4] + h2 * sa[5];                       // s2
    ((_Float16*)((char*)ws + WS_HX_OFF))[i] = (_Float16)h0;
    ((_Float16*)((char*)ws + WS_HY_OFF))[i] = (_Float16)h1;
    ((_Float16*)((char*)ws + WS_HZ_OFF))[i] = (_Float16)h2;
    ws[WS_S1_OFF / 4 + i] = h0 * sa[0] + h1 * sa[1] + h2 * sa[2];       // s1
}

// 1000 blocks; block covers 16 CONSECUTIVE adj rows (same batch b, i_base..i_base+15):
// 128 KB contiguous per block. Wave w owns rows i_base+4w..+3 (32 KB contiguous, 4
// streams 8 KB apart advancing sequentially). Chunk-outer/row-inner: LDS table reads
// and fp16 cvts shared across the 4 rows; exps per (row,q).
__global__ __launch_bounds__(256, 5) void k_main(const float* __restrict__ emb,
                                                 const float* __restrict__ W,
                                                 const float* __restrict__ a,
                                                 const float* __restrict__ fc1_w,
                                                 const int*   __restrict__ adj,
                                                 float* __restrict__ wsf,
                                                 int mode,
                                                 float* __restrict__ out) {
    __shared__ __align__(16) unsigned char smem[20480];
    float*    s2s = (float*)smem;
    _Float16* hxs = (_Float16*)(smem + 8192);
    _Float16* hys = (_Float16*)(smem + 12288);
    _Float16* hzs = (_Float16*)(smem + 16384);
    __shared__ float sW[GAT_EMB * 3];
    __shared__ float sa[6];
    __shared__ float s1sh[16];
    __shared__ float xblk[48];       // x[b][3*(i-i_base)+d] for this block's b

    int t = threadIdx.x;
    int R0 = blockIdx.x * 16;        // global row index (b*N_ENT + i)
    int b  = R0 / N_ENT;             // 16 | 2000 -> no straddle
    int i_base = R0 - b * N_ENT;

    if (mode != 0) {
        const uint4* src = (const uint4*)wsf;
        uint4* dst = (uint4*)smem;
#pragma unroll
        for (int rep = 0; rep < 5; ++rep) dst[rep * 256 + t] = src[rep * 256 + t];  // 20480 B
        if (t < 16) s1sh[t] = wsf[WS_S1_OFF / 4 + i_base + t];
    } else {
        if (t < GAT_EMB * 3) sW[t] = W[t];
        if (t < 6)           sa[t] = a[t];
        __syncthreads();
        for (int j = t; j < N_ENT; j += 256) {
            const float4* er = (const float4*)(emb + (size_t)j * GAT_EMB);
            float h0 = 0.f, h1 = 0.f, h2 = 0.f;
#pragma unroll
            for (int k4 = 0; k4 < GAT_EMB / 4; ++k4) {
                float4 e4 = er[k4];
                int k = 4 * k4;
                h0 += e4.x * sW[(k + 0) * 3 + 0]; h1 += e4.x * sW[(k + 0) * 3 + 1]; h2 += e4.x * sW[(k + 0) * 3 + 2];
                h0 += e4.y * sW[(k + 1) * 3 + 0]; h1 += e4.y * sW[(k + 1) * 3 + 1]; h2 += e4.y * sW[(k + 1) * 3 + 2];
                h0 += e4.z * sW[(k + 2) * 3 + 0]; h1 += e4.z * sW[(k + 2) * 3 + 1]; h2 += e4.z * sW[(k + 2) * 3 + 2];
                h0 += e4.w * sW[(k + 3) * 3 + 0]; h1 += e4.w * sW[(k + 3) * 3 + 1]; h2 += e4.w * sW[(k + 3) * 3 + 2];
            }
            s2s[j] = h0 * sa[3] + h1 * sa[4] + h2 * sa[5];
            hxs[j] = (_Float16)h0; hys[j] = (_Float16)h1; hzs[j] = (_Float16)h2;
            if (j >= i_base && j < i_base + 16)
                s1sh[j - i_base] = h0 * sa[0] + h1 * sa[1] + h2 * sa[2];
        }
    }
    if (t < 2048 - N_ENT) {   // zero the pad
        int j = N_ENT + t;
        s2s[j] = 0.f; hxs[j] = (_Float16)0; hys[j] = (_Float16)0; hzs[j] = (_Float16)0;
    }
    __syncthreads();

    // ---- Phase 2 ----
    int lane = t & 63;
    int w    = t >> 6;
    float s1r[4];
    const int* __restrict__ rowp[4];
#pragma unroll
    for (int r = 0; r < 4; ++r) {
        s1r[r] = s1sh[4 * w + r];
        rowp[r] = adj + ((size_t)b * N_ENT + (i_base + 4 * w + r)) * N_ENT;
    }

    float acc[4][4];
#pragma unroll
    for (int r = 0; r < 4; ++r) { acc[r][0] = 0.f; acc[r][1] = 0.f; acc[r][2] = 0.f; acc[r][3] = 0.f; }

    int l4 = lane << 2;
#pragma unroll
    for (int c = 0; c < 8; ++c) {
        int j0 = c * 256 + l4;            // <= 2044; LDS pad zeroed
        bool chunk_full = (c != 7);
        bool valid = chunk_full | (j0 < N_ENT);
        int jc = valid ? j0 : 0;

        int4 m0 = *(const int4*)(rowp[0] + jc);   // 4 streams, 8 KB apart, sequential in c
        int4 m1 = *(const int4*)(rowp[1] + jc);
        int4 m2 = *(const int4*)(rowp[2] + jc);
        int4 m3 = *(const int4*)(rowp[3] + jc);

        float4 s2v = *(const float4*)&s2s[j0];
        half4  hxv = *(const half4*)&hxs[j0];
        half4  hyv = *(const half4*)&hys[j0];
        half4  hzv = *(const half4*)&hzs[j0];
        float hx[4], hy[4], hz[4];
#pragma unroll
        for (int q = 0; q < 4; ++q) { hx[q] = (float)hxv[q]; hy[q] = (float)hyv[q]; hz[q] = (float)hzv[q]; }

        const int* mm[4] = { (const int*)&m0, (const int*)&m1, (const int*)&m2, (const int*)&m3 };
        float vw = valid ? 1.0f : 0.0f;
#pragma unroll
        for (int r = 0; r < 4; ++r) {
#pragma unroll
            for (int q = 0; q < 4; ++q) {
                float e  = s1r[r] + ((const float*)&s2v)[q];
                float ev = __expf(fmaxf(e, 0.f) + ALPHA * fminf(e, 0.f));
                float contrib = (mm[r][q] > 0) ? ev : 1.0f;   // expf(9e-15)==1.0f exactly
                if (!chunk_full) contrib *= vw;
                acc[r][0] += contrib;
                acc[r][1] += contrib * hx[q];
                acc[r][2] += contrib * hy[q];
                acc[r][3] += contrib * hz[q];
            }
        }
    }

#pragma unroll
    for (int off = 32; off > 0; off >>= 1)
#pragma unroll
        for (int r = 0; r < 4; ++r) {
            acc[r][0] += __shfl_xor(acc[r][0], off, 64);
            acc[r][1] += __shfl_xor(acc[r][1], off, 64);
            acc[r][2] += __shfl_xor(acc[r][2], off, 64);
            acc[r][3] += __shfl_xor(acc[r][3], off, 64);
        }

    if (lane == 0) {
#pragma unroll
        for (int r = 0; r < 4; ++r) {
            float inv = 1.f / acc[r][0];
            float p0 = acc[r][1] * inv, p1 = acc[r][2] * inv, p2 = acc[r][3] * inv;
            p0 = (p0 > 0.f) ? p0 : expm1f(p0);   // ELU
            p1 = (p1 > 0.f) ? p1 : expm1f(p1);
            p2 = (p2 > 0.f) ? p2 : expm1f(p2);
            int c = 3 * (4 * w + r);
            if (mode == 2) {
                _Float16* x16 = (_Float16*)((char*)wsf + WS_X_OFF);
                int i = i_base + 4 * w + r;
                x16[(size_t)(3 * i + 0) * 8 + b] = (_Float16)p0;
                x16[(size_t)(3 * i + 1) * 8 + b] = (_Float16)p1;
                x16[(size_t)(3 * i + 2) * 8 + b] = (_Float16)p2;
            } else {
                xblk[c + 0] = p0; xblk[c + 1] = p1; xblk[c + 2] = p2;
            }
        }
    }

    if (mode != 2) {   // fallback: atomic FC for this block's 48 columns, one batch b
        __syncthreads();
        int k = (t + R0) & 255;
        const float* wr = fc1_w + (size_t)k * (N_ENT * 3) + 3 * i_base;   // 48 floats, 16B-aligned (48|12)
        float d = 0.f;
#pragma unroll
        for (int c4 = 0; c4 < 12; ++c4) {
            float4 wv = *(const float4*)(wr + 4 * c4);
            d += xblk[4 * c4 + 0] * wv.x + xblk[4 * c4 + 1] * wv.y
               + xblk[4 * c4 + 2] * wv.z + xblk[4 * c4 + 3] * wv.w;
        }
        atomicAdd(&out[b * HIDDEN + k], d);
    }
}

// out[b,k] = fc1_b[k] + sum_m x16[m][b] * fc1_w[k][m]; 256 blocks (one per k).
__global__ __launch_bounds__(256) void k_fc(const _Float16* __restrict__ x16,
                                            const float* __restrict__ fc1_w,
                                            const float* __restrict__ fc1_b,
                                            float* __restrict__ out) {
    __shared__ float red[4][8];
    int t = threadIdx.x, lane = t & 63, w = t >> 6;
    int k = blockIdx.x;
    const float* __restrict__ wr = fc1_w + (size_t)k * (N_ENT * 3);
    float acc[BATCH];
#pragma unroll
    for (int b = 0; b < BATCH; ++b) acc[b] = 0.f;
#pragma unroll
    for (int it = 0; it < 6; ++it) {
        int m0 = 4 * t + 1024 * it;
        if (m0 + 3 < N_ENT * 3) {
            float4 wv4 = *(const float4*)(wr + m0);
#pragma unroll
            for (int q = 0; q < 4; ++q) {
                half4 xa = *(const half4*)(x16 + (size_t)(m0 + q) * 8);
                half4 xb = *(const half4*)(x16 + (size_t)(m0 + q) * 8 + 4);
                float wv = ((const float*)&wv4)[q];
                acc[0] += wv * (float)xa[0]; acc[1] += wv * (float)xa[1];
                acc[2] += wv * (float)xa[2]; acc[3] += wv * (float)xa[3];
                acc[4] += wv * (float)xb[0]; acc[5] += wv * (float)xb[1];
                acc[6] += wv * (float)xb[2]; acc[7] += wv * (float)xb[3];
            }
        }
    }
#pragma unroll
    for (int off = 32; off > 0; off >>= 1)
#pragma unroll
        for (int b = 0; b < BATCH; ++b) acc[b] += __shfl_xor(acc[b], off, 64);
    if (lane == 0)
#pragma unroll
        for (int b = 0; b < BATCH; ++b) red[w][b] = acc[b];
    __syncthreads();
    if (t < 8)
        out[t * HIDDEN + k] = red[0][t] + red[1][t] + red[2][t] + red[3][t] + fc1_b[k];
}

extern "C" void kernel_launch(void* const* d_in, const int* in_sizes, int n_in,
                              void* d_out, int out_size, void* d_ws, size_t ws_size,
                              hipStream_t stream) {
    const float* emb   = (const float*)d_in[0];
    const float* W     = (const float*)d_in[1];
    const float* a     = (const float*)d_in[2];
    const float* fc1_w = (const float*)d_in[3];
    const float* fc1_b = (const float*)d_in[4];
    const int*   adj   = (const int*)d_in[5];
    float* out = (float*)d_out;
    float* ws  = (float*)d_ws;
    (void)in_sizes; (void)n_in; (void)out_size;

    int tier = (ws_size >= (size_t)WS_TIER2_BYTES) ? 2
             : (ws_size >= (size_t)WS_TABLE_BYTES) ? 1 : 0;

    if (tier < 2)  k_init<<<8, 256, 0, stream>>>(fc1_b, out);
    if (tier >= 1) k_prep<<<8, 256, 0, stream>>>(emb, W, a, ws);
    k_main<<<1000, 256, 0, stream>>>(emb, W, a, fc1_w, adj, ws, tier, out);
    if (tier == 2)
        k_fc<<<HIDDEN, 256, 0, stream>>>((const _Float16*)((char*)d_ws + WS_X_OFF),
                                         fc1_w, fc1_b, out);
}